// Round 7
// baseline (740.083 us; speedup 1.0000x reference)
//
#include <hip/hip_runtime.h>

// ============================================================================
// CharLevelEncoder R7: weight-stationary persistent LSTM, 512 thr (R5 base).
// - K=64 i8 MFMA; W: 4/5 in VGPR (128 regs) + 1/5 in LDS (64 KB).
// - 8-stage (mt,cc) software pipeline w/ double acc: MFMA(s+1) overlaps
//   trans(s)  [R5 evidence: single acc set => zero pipe overlap].
// - double-buffered Xb => 1 barrier/step; frozen rows refresh final h at
//   t==len so both buffers stay valid.
// - trans reduced 10->8 per unit-step via shared-rcp algebra.
// ============================================================================

#define NW 32768

typedef __attribute__((ext_vector_type(8))) short short8;
typedef __attribute__((ext_vector_type(4))) float f32x4;
typedef __attribute__((ext_vector_type(4))) int i32x4;

#define MFMA16(a,b,c)  __builtin_amdgcn_mfma_f32_16x16x32_bf16(a,b,c,0,0,0)
#define MFMAI64(a,b,c) __builtin_amdgcn_mfma_i32_16x16x64_i8(a,b,c,0,0,0)

// ---- workspace layout (bytes) ----
#define O_ORDER 0                      // i32[32768] sorted word ids (asc len)
#define O_SLEN  131072                 // i32[32768] sorted lengths
#define O_WPK   262144                 // i8 packed W' K64-fragments (327680)
#define O_USTP  589824                 // f32[1024] rowmax/(127*127)
#define O_BIAS  593920                 // f32[1024] b_ih + b_hh
#define O_CHT   598016                 // i8[256][64] chartab = rint(508*E)
#define O_WLIN  614400                 // bf16 packed W_lin fragments (262144)

__device__ inline unsigned short f2b(float f) {   // fp32 -> bf16 RNE
  unsigned u = __builtin_bit_cast(unsigned, f);
  u = u + 0x7fffu + ((u >> 16) & 1u);
  return (unsigned short)(u >> 16);
}

// ---- prepA: row scales (wave-per-row), bias, chartab ----
__global__ void k_prepA(const float* __restrict__ wih, const float* __restrict__ whh,
                        const float* __restrict__ bih, const float* __restrict__ bhh,
                        const float* __restrict__ ech, unsigned char* __restrict__ ws) {
  int b = blockIdx.x, tid = threadIdx.x;
  if (b < 256) {                        // 4 waves/block, wave-per-row rowmax
    int n = b * 4 + (tid >> 6), lane = tid & 63;
    float m = fabsf(wih[n * 64 + lane]) * 0.25f;
    #pragma unroll
    for (int c = 0; c < 4; ++c) m = fmaxf(m, fabsf(whh[n * 256 + c * 64 + lane]));
    #pragma unroll
    for (int off = 32; off; off >>= 1) m = fmaxf(m, __shfl_xor(m, off));
    if (lane == 0) {
      ((float*)(ws + O_USTP))[n] = m / 16129.f;    // rowmax/(127*127)
      ((float*)(ws + O_BIAS))[n] = bih[n] + bhh[n];
    }
    return;
  }
  int idx = (b - 256) * 256 + tid;      // chartab: rint(508*E) clamp ±127
  int q = (int)__builtin_rintf(508.f * ech[idx]);
  q = q < -127 ? -127 : (q > 127 ? 127 : q);
  ((signed char*)(ws + O_CHT))[idx] = (signed char)q;
}

// ---- prepB: pack W' i8 K64-frags (R7 order) + W_lin bf16 frags ----
// WPK flat byte: (((w*5+kb)*8+f)*64+lane)*16 + j, f = g*2+cc
//   n = g*256 + w*32 + cc*16 + (lane&15);  k = kb*64 + (lane>>4)*16 + j
__global__ void k_prepB(const float* __restrict__ wih, const float* __restrict__ whh,
                        const float* __restrict__ wlin, unsigned char* __restrict__ ws) {
  int i = blockIdx.x * 256 + threadIdx.x;
  if (i < 327680) {
    int j = i & 15, lane = (i >> 4) & 63, t = i >> 10;
    int f = t & 7, u = t >> 3;
    int kb = u % 5, w = u / 5;
    int g = f >> 1, cc = f & 1;
    int n = g * 256 + w * 32 + cc * 16 + (lane & 15);
    int k = kb * 64 + (lane >> 4) * 16 + j;
    float v = (k < 64) ? wih[n * 64 + k] * 0.25f : whh[n * 256 + (k - 64)];
    float ustep = ((const float*)(ws + O_USTP))[n] * 127.f;
    float qf = (ustep > 0.f) ? v / ustep : 0.f;
    int q = (int)__builtin_rintf(qf);
    q = q < -127 ? -127 : (q > 127 ? 127 : q);
    ((signed char*)(ws + O_WPK))[i] = (signed char)q;
    return;
  }
  int i2 = i - 327680;                  // W_lin pack (layout verified R4-R6)
  int j = i2 & 7, lane = (i2 >> 3) & 63, t3 = i2 >> 9;
  int kf = t3 & 15, nn = t3 >> 4;
  int n = (nn >> 2) * 64 + (nn & 3) * 16 + (lane & 15);
  int k = kf * 32 + (lane >> 4) * 8 + j;
  ((unsigned short*)(ws + O_WLIN))[i2] = f2b(wlin[n * 512 + k]);
}

// ---- single-block counting sort by length ----
__global__ void k_sort(const int* __restrict__ lens, unsigned char* __restrict__ ws) {
  __shared__ unsigned hist[16], pos[16];
  int tid = threadIdx.x;
  if (tid < 16) hist[tid] = 0;
  __syncthreads();
  for (int w = tid; w < NW; w += 1024) {
    int l = lens[w]; l = l < 1 ? 1 : (l > 16 ? 16 : l);
    atomicAdd(&hist[l - 1], 1u);
  }
  __syncthreads();
  if (tid == 0) {
    unsigned acc = 0;
    for (int l = 0; l < 16; ++l) { pos[l] = acc; acc += hist[l]; }
  }
  __syncthreads();
  int* order = (int*)(ws + O_ORDER);
  int* slenp = (int*)(ws + O_SLEN);
  for (int w = tid; w < NW; w += 1024) {
    int l = lens[w]; l = l < 1 ? 1 : (l > 16 ? 16 : l);
    unsigned p = atomicAdd(&pos[l - 1], 1u);
    order[p] = w; slenp[p] = l;
  }
}

// ---- main: 256 blocks x 512 threads (8 waves), 64 words/block ----
// LDS: Xb[2][4][5][64][16] 40K | WL[8][8][64][16] 64K | CT 16K | CW 4K = 124K
#define L_WL 40960
#define L_CT 106496
#define L_CW 122880

__global__ __launch_bounds__(512, 2) void k_main(
    const int* __restrict__ cidx, const float* __restrict__ wemb,
    const float* __restrict__ blin, float* __restrict__ outp,
    const unsigned char* __restrict__ ws) {
  extern __shared__ unsigned char smem[];
  signed char (*Xb)[4][5][64][16] = (signed char (*)[4][5][64][16])smem;
  signed char (*WL)[8][64][16]    = (signed char (*)[8][64][16])(smem + L_WL);
  signed char (*CT)[64]           = (signed char (*)[64])(smem + L_CT);
  int (*CW)[16]                   = (int (*)[16])(smem + L_CW);

  const int tid = threadIdx.x, b = blockIdx.x;
  const int w = tid >> 6, lane = tid & 63;
  const int q = lane >> 4, l15 = lane & 15;

  const int* order = (const int*)(ws + O_ORDER);
  const int* slen  = (const int*)(ws + O_SLEN);
  const signed char* wpk = (const signed char*)(ws + O_WPK);
  const unsigned short* wlin = (const unsigned short*)(ws + O_WLIN);

  // ---- prologue: CT -> LDS, W kb0-3 -> VGPR, W kb4 -> LDS, consts ----
  ((i32x4*)CT)[tid]       = ((const i32x4*)(ws + O_CHT))[tid];
  ((i32x4*)CT)[512 + tid] = ((const i32x4*)(ws + O_CHT))[512 + tid];
  i32x4 wreg[4][8];
  #pragma unroll
  for (int kb = 0; kb < 4; ++kb)
    #pragma unroll
    for (int f = 0; f < 8; ++f)
      wreg[kb][f] = *(const i32x4*)(wpk + (((w * 5 + kb) * 8 + f) * 64 + lane) * 16);
  #pragma unroll
  for (int f = 0; f < 8; ++f)
    *(i32x4*)&WL[w][f][lane][0] =
        *(const i32x4*)(wpk + (((w * 5 + 4) * 8 + f) * 64 + lane) * 16);
  float uq[2][4], bq[2][4];
  #pragma unroll
  for (int cc = 0; cc < 2; ++cc)
    #pragma unroll
    for (int g = 0; g < 4; ++g) {
      int n = g * 256 + w * 32 + cc * 16 + l15;
      uq[cc][g] = ((const float*)(ws + O_USTP))[n];
      bq[cc][g] = ((const float*)(ws + O_BIAS))[n];
    }
  const int mh = w >> 2, nw = w & 3;
  float blv[4];
  #pragma unroll
  for (int nt = 0; nt < 4; ++nt) blv[nt] = blin[nw * 64 + nt * 16 + l15];

  // ---- two balanced slices {b, 511-b} ----
  for (int sl = 0; sl < 2; ++sl) {
    const int s = sl ? (511 - b) : b;
    const int base = 64 * s;
    __syncthreads();                   // prologue / prev epilogue done

    { // zero buf0 h-region (kb1..4, all mt): 1024 x 16B
      #pragma unroll
      for (int ii = 0; ii < 2; ++ii) {
        int idx = tid + 512 * ii;
        int mt = idx >> 8, off = idx & 255;
        *(i32x4*)(&Xb[0][mt][1][0][0] + off * 16) = (i32x4)0;
      }
    }
    if (tid < 256) {                   // char indices for this slice
      int m = tid >> 2, part = tid & 3;
      int wid = order[base + m];
      *(i32x4*)&CW[m][part * 4] = *(const i32x4*)(cidx + wid * 16 + part * 4);
    }
    unsigned lenpk[4];
    #pragma unroll
    for (int mt = 0; mt < 4; ++mt) {
      int pbm = base + 16 * mt;
      unsigned l0 = (unsigned)slen[pbm + q * 4 + 0];
      unsigned l1 = (unsigned)slen[pbm + q * 4 + 1];
      unsigned l2 = (unsigned)slen[pbm + q * 4 + 2];
      unsigned l3 = (unsigned)slen[pbm + q * 4 + 3];
      lenpk[mt] = l0 | (l1 << 8) | (l2 << 16) | (l3 << 24);
    }
    const int Tm = slen[base + 63];
    __syncthreads();
    if (tid < 256) {                   // stage x' for t=0 into buf0
      int m = tid >> 2, c = tid & 3;
      int ch = CW[m][0] & 255;
      *(i32x4*)&Xb[0][m >> 4][0][(m & 15) + 16 * c][0] = *(const i32x4*)&CT[ch][c * 16];
    }
    __syncthreads();

    f32x4 creg[4][2];                  // cell state [mt][cc].r
    #pragma unroll
    for (int mt = 0; mt < 4; ++mt)
      #pragma unroll
      for (int cc = 0; cc < 2; ++cc) creg[mt][cc] = 0.0f;
    unsigned fhold[4][2] = {};         // packed final-h bytes per [mt][cc]

    for (int t = 0; t < Tm; ++t) {
      const int cur = t & 1, nxt = cur ^ 1;
      i32x4 acc0[4], acc1[4];

      auto stage_mfma = [&](int mt, int cc, i32x4* acc) {
        #pragma unroll
        for (int g = 0; g < 4; ++g) acc[g] = (i32x4)0;
        #pragma unroll
        for (int kb = 0; kb < 5; ++kb) {
          i32x4 A = *(const i32x4*)&Xb[cur][mt][kb][lane][0];
          if (kb < 4) {
            #pragma unroll
            for (int g = 0; g < 4; ++g)
              acc[g] = MFMAI64(A, wreg[kb][g * 2 + cc], acc[g]);
          } else {
            #pragma unroll
            for (int g = 0; g < 4; ++g) {
              i32x4 Bv = *(const i32x4*)&WL[w][g * 2 + cc][lane][0];
              acc[g] = MFMAI64(A, Bv, acc[g]);
            }
          }
        }
      };
      auto stage_update = [&](int mt, int cc, i32x4* acc) {
        const int kbh = 1 + ((w * 2 + cc) >> 2);
        const int sub = (4 + w * 2 + cc) & 3;
        unsigned fh = fhold[mt][cc], newf = 0;
        #pragma unroll
        for (int r = 0; r < 4; ++r) {
          float gi = (float)acc[0][r] * uq[cc][0] + bq[cc][0];
          float gf = (float)acc[1][r] * uq[cc][1] + bq[cc][1];
          float gg = (float)acc[2][r] * uq[cc][2] + bq[cc][2];
          float go = (float)acc[3][r] * uq[cc][3] + bq[cc][3];
          gi = fminf(30.f, fmaxf(-30.f, gi));
          gf = fminf(30.f, fmaxf(-30.f, gf));
          gg = fminf(30.f, fmaxf(-30.f, gg));
          go = fminf(30.f, fmaxf(-30.f, go));
          float ei  = __builtin_amdgcn_exp2f(-1.44269504f * gi);
          float ef  = __builtin_amdgcn_exp2f(-1.44269504f * gf);
          float eg2 = __builtin_amdgcn_exp2f( 2.88539008f * gg);
          float eo  = __builtin_amdgcn_exp2f(-1.44269504f * go);
          float cold = creg[mt][cc][r];
          float cn = cold * __builtin_amdgcn_rcpf(1.f + ef) +
                     (eg2 - 1.f) * __builtin_amdgcn_rcpf((1.f + ei) * (1.f + eg2));
          float ec = __builtin_amdgcn_exp2f(2.88539008f * cn);
          float hn = (ec - 1.f) * __builtin_amdgcn_rcpf((1.f + eo) * (ec + 1.f));
          int lene = (int)((lenpk[mt] >> (8 * r)) & 255u);
          bool act = t < lene;
          creg[mt][cc][r] = act ? cn : cold;
          int hq = (int)__builtin_rintf(127.f * hn);
          hq = hq < -127 ? -127 : (hq > 127 ? 127 : hq);
          unsigned ob = act ? ((unsigned)hq & 255u) : ((fh >> (8 * r)) & 255u);
          newf |= ob << (8 * r);
          if (t <= lene)               // fresh h, or one-time final-h refresh
            Xb[nxt][mt][kbh][(q * 4 + r) + 16 * sub][l15] = (signed char)ob;
        }
        fhold[mt][cc] = newf;
      };

      // 8-stage pipeline: MFMA(s+1) overlaps trans/update(s)
      stage_mfma(0, 0, acc0);
      #pragma unroll
      for (int s2 = 0; s2 < 8; ++s2) {
        i32x4* curA = (s2 & 1) ? acc1 : acc0;
        i32x4* nxtA = (s2 & 1) ? acc0 : acc1;
        if (s2 < 7) stage_mfma((s2 + 1) >> 1, (s2 + 1) & 1, nxtA);
        stage_update(s2 >> 1, s2 & 1, curA);
      }
      if (t + 1 < Tm && tid < 256) {   // stage x' for t+1 into buf nxt
        int m = tid >> 2, c = tid & 3;
        int ch = CW[m][t + 1] & 255;
        *(i32x4*)&Xb[nxt][m >> 4][0][(m & 15) + 16 * c][0] = *(const i32x4*)&CT[ch][c * 16];
      }
      __syncthreads();                 // single barrier per step
    } // t

    // ---- fused final linear (reads h from Xb[Tm&1]) ----
    const int e = Tm & 1;
    int widA[2];
    #pragma unroll
    for (int mi = 0; mi < 2; ++mi) widA[mi] = order[base + (2 * mh + mi) * 16 + l15];
    f32x4 fac[2][4];
    #pragma unroll
    for (int mi = 0; mi < 2; ++mi)
      #pragma unroll
      for (int nt = 0; nt < 4; ++nt) fac[mi][nt] = 0.0f;

    #pragma unroll
    for (int kf = 0; kf < 16; ++kf) {              // K = 512
      short8 Bn[4];
      #pragma unroll
      for (int nt = 0; nt < 4; ++nt)
        Bn[nt] = ((const short8*)wlin)[((nw * 4 + nt) * 16 + kf) * 64 + lane];
      short8 Am[2];
      #pragma unroll
      for (int mi = 0; mi < 2; ++mi) {
        if (kf < 8) {                  // word_emb fp32 -> bf16
          const f32x4* pa = (const f32x4*)(wemb + widA[mi] * 256 + kf * 32 + q * 8);
          f32x4 f0 = pa[0], f1 = pa[1];
          short8 A;
          A[0] = (short)f2b(f0[0]); A[1] = (short)f2b(f0[1]);
          A[2] = (short)f2b(f0[2]); A[3] = (short)f2b(f0[3]);
          A[4] = (short)f2b(f1[0]); A[5] = (short)f2b(f1[1]);
          A[6] = (short)f2b(f1[2]); A[7] = (short)f2b(f1[3]);
          Am[mi] = A;
        } else {                       // final h from Xb i8 (K64 layout)
          int K0 = 64 + (kf - 8) * 32 + q * 8;
          long ch = *(const long*)&Xb[e][2 * mh + mi][K0 >> 6]
                                     [l15 + 16 * ((K0 >> 4) & 3)][K0 & 15];
          short8 A;
          #pragma unroll
          for (int j = 0; j < 8; ++j) {
            int v = (int)(signed char)((ch >> (8 * j)) & 255);
            A[j] = (short)f2b((float)v * (1.f / 127.f));
          }
          Am[mi] = A;
        }
      }
      #pragma unroll
      for (int mi = 0; mi < 2; ++mi)
        #pragma unroll
        for (int nt = 0; nt < 4; ++nt)
          fac[mi][nt] = MFMA16(Am[mi], Bn[nt], fac[mi][nt]);
    }
    #pragma unroll
    for (int mi = 0; mi < 2; ++mi) {
      #pragma unroll
      for (int r = 0; r < 4; ++r) {
        int wid = order[base + (2 * mh + mi) * 16 + q * 4 + r];
        float* po = outp + wid * 256 + nw * 64 + l15;
        #pragma unroll
        for (int nt = 0; nt < 4; ++nt) {
          float v = fac[mi][nt][r] + blv[nt];
          po[nt * 16] = v > 0.f ? v : 0.f;
        }
      }
    }
  } // slice
}

extern "C" void kernel_launch(void* const* d_in, const int* in_sizes, int n_in,
                              void* d_out, int out_size, void* d_ws, size_t ws_size,
                              hipStream_t stream) {
  const int*   cidx = (const int*)d_in[0];
  const int*   clen = (const int*)d_in[1];
  const float* wemb = (const float*)d_in[2];
  const float* ech  = (const float*)d_in[3];
  const float* wih  = (const float*)d_in[4];
  const float* whh  = (const float*)d_in[5];
  const float* bih  = (const float*)d_in[6];
  const float* bhh  = (const float*)d_in[7];
  const float* wlin = (const float*)d_in[8];
  const float* blin = (const float*)d_in[9];
  float* outp = (float*)d_out;
  unsigned char* ws = (unsigned char*)d_ws;

  k_prepA<<<320, 256, 0, stream>>>(wih, whh, bih, bhh, ech, ws);
  k_prepB<<<1792, 256, 0, stream>>>(wih, whh, wlin, ws);
  k_sort<<<1, 1024, 0, stream>>>(clen, ws);
  k_main<<<256, 512, 126976, stream>>>(cidx, wemb, blin, outp, ws);
}

// Round 8
// 730.265 us; speedup vs baseline: 1.0134x; 1.0134x over previous
//
#include <hip/hip_runtime.h>

// ============================================================================
// CharLevelEncoder R8 = R5 (best: 323 us k_main) + three safe deltas:
//  1. remove wave-uniform per-tile `continue` branches in the t-loop ->
//     one basic block, compiler interleaves the 4 independent tile chains
//     (R5 evidence: 45.6k cyc/step vs ~11k pipe work = stall-bound, 2 w/SIMD).
//  2. gate algebra 10 -> 8 transcendentals (validated numerically in R7).
//  3. parallel prep kernels (R5's serial rowmax cost ~55 us of overhead).
// R6/R7 lesson encoded: keep live state under ~130 VGPR/wave; no manual
// pipelining, no 16-wave variants (compiler spills; FETCH tripwire >300 MB).
// ============================================================================

#define NW 32768

typedef __attribute__((ext_vector_type(8))) short short8;
typedef __attribute__((ext_vector_type(4))) float f32x4;
typedef __attribute__((ext_vector_type(4))) int i32x4;

#define MFMA16(a,b,c) __builtin_amdgcn_mfma_f32_16x16x32_bf16(a,b,c,0,0,0)
#define MFMAI8(a,b,c) __builtin_amdgcn_mfma_i32_16x16x32_i8(a,b,c,0,0,0)

// ---- workspace layout (bytes) ----
#define O_ORDER 0                      // i32[32768] sorted word ids (asc len)
#define O_SLEN  131072                 // i32[32768] sorted lengths
#define O_WPK   262144                 // i8 packed W' fragments (327680)
#define O_USTP  589824                 // f32[1024] rowmax/(127*127)
#define O_BIAS  593920                 // f32[1024] b_ih + b_hh
#define O_CHT   598016                 // i8[256][64] chartab = rint(508*E)
#define O_WLIN  614400                 // bf16 packed W_lin fragments (262144)

__device__ inline unsigned short f2b(float f) {   // fp32 -> bf16 RNE
  unsigned u = __builtin_bit_cast(unsigned, f);
  u = u + 0x7fffu + ((u >> 16) & 1u);
  return (unsigned short)(u >> 16);
}

// ---- prepA: row scales (wave-per-row), bias, chartab (parallel) ----
__global__ void k_prepA(const float* __restrict__ wih, const float* __restrict__ whh,
                        const float* __restrict__ bih, const float* __restrict__ bhh,
                        const float* __restrict__ ech, unsigned char* __restrict__ ws) {
  int b = blockIdx.x, tid = threadIdx.x;
  if (b < 256) {                        // 4 waves/block, wave-per-row rowmax
    int n = b * 4 + (tid >> 6), lane = tid & 63;
    float m = fabsf(wih[n * 64 + lane]) * 0.25f;
    #pragma unroll
    for (int c = 0; c < 4; ++c) m = fmaxf(m, fabsf(whh[n * 256 + c * 64 + lane]));
    #pragma unroll
    for (int off = 32; off; off >>= 1) m = fmaxf(m, __shfl_xor(m, off));
    if (lane == 0) {
      ((float*)(ws + O_USTP))[n] = m / 16129.f;    // rowmax/(127*127)
      ((float*)(ws + O_BIAS))[n] = bih[n] + bhh[n];
    }
    return;
  }
  int idx = (b - 256) * 256 + tid;      // chartab: rint(508*E) clamp ±127
  int q = (int)__builtin_rintf(508.f * ech[idx]);
  q = q < -127 ? -127 : (q > 127 ? 127 : q);
  ((signed char*)(ws + O_CHT))[idx] = (signed char)q;
}

// ---- prep1: pack W' i8 fragments + W_lin bf16 fragments (R5 layout) ----
// WPK flat: (((w*10+kb)*8+nt)*64+lane)*8+j ; n=(nt>>1)*256+w*32+(nt&1)*16+(lane&15)
//           k = kb*32+(lane>>4)*8+j ; val = k<64 ? wih/4 : whh
__global__ void k_prep1(const float* __restrict__ wih, const float* __restrict__ whh,
                        const float* __restrict__ wlin, unsigned char* __restrict__ ws) {
  int i = blockIdx.x * 256 + threadIdx.x;
  if (i < 327680) {
    int j = i & 7, lane = (i >> 3) & 63, t2 = i >> 9;
    int nt = t2 & 7, u2 = t2 >> 3;
    int kb = u2 % 10, w = u2 / 10;
    int n = (nt >> 1) * 256 + w * 32 + (nt & 1) * 16 + (lane & 15);
    int k = kb * 32 + (lane >> 4) * 8 + j;
    float v = (k < 64) ? wih[n * 64 + k] * 0.25f : whh[n * 256 + (k - 64)];
    float ustep = ((const float*)(ws + O_USTP))[n] * 127.f;  // rowmax/127
    float qf = (ustep > 0.f) ? v / ustep : 0.f;
    int q = (int)__builtin_rintf(qf);
    q = q < -127 ? -127 : (q > 127 ? 127 : q);
    ((signed char*)(ws + O_WPK))[i] = (signed char)q;
    return;
  }
  int i2 = i - 327680;                  // W_lin pack (layout verified R4/R5)
  int j = i2 & 7, lane = (i2 >> 3) & 63, t3 = i2 >> 9;
  int kf = t3 & 15, nn = t3 >> 4;
  int n = (nn >> 2) * 64 + (nn & 3) * 16 + (lane & 15);
  int k = kf * 32 + (lane >> 4) * 8 + j;
  ((unsigned short*)(ws + O_WLIN))[i2] = f2b(wlin[n * 512 + k]);
}

// ---- counting sort by length ----
__global__ void k_sort(const int* __restrict__ lens, unsigned char* __restrict__ ws) {
  __shared__ unsigned hist[16], pos[16];
  int tid = threadIdx.x;
  if (tid < 16) hist[tid] = 0;
  __syncthreads();
  for (int w = tid; w < NW; w += 1024) {
    int l = lens[w]; l = l < 1 ? 1 : (l > 16 ? 16 : l);
    atomicAdd(&hist[l - 1], 1u);
  }
  __syncthreads();
  if (tid == 0) {
    unsigned acc = 0;
    for (int l = 0; l < 16; ++l) { pos[l] = acc; acc += hist[l]; }
  }
  __syncthreads();
  int* order = (int*)(ws + O_ORDER);
  int* slenp = (int*)(ws + O_SLEN);
  for (int w = tid; w < NW; w += 1024) {
    int l = lens[w]; l = l < 1 ? 1 : (l > 16 ? 16 : l);
    unsigned p = atomicAdd(&pos[l - 1], 1u);
    order[p] = w; slenp[p] = l;
  }
}

// ---- main persistent kernel: 256 blocks x 512 threads ----
__global__ __launch_bounds__(512, 2) void k_main(
    const int* __restrict__ cidx, const float* __restrict__ wemb,
    const float* __restrict__ blin, float* __restrict__ outp,
    const unsigned char* __restrict__ ws) {
  extern __shared__ signed char smem[];
  // WL: [kb-7][w][nt][lane][8]  96 KB  (W' kb 7..9)
  signed char (*WL)[8][8][64][8] = (signed char (*)[8][8][64][8])smem;
  // Xb: [mt][kb][ (m&15)+16*((k&31)>>3) ][ (k&31)&7 ]  i8  20 KB
  signed char (*Xb)[10][64][8] = (signed char (*)[10][64][8])(smem + 98304);
  signed char (*CT)[64] = (signed char (*)[64])(smem + 98304 + 20480);  // 16 KB
  int (*CW)[16] = (int (*)[16])(smem + 98304 + 20480 + 16384);          //  4 KB

  const int tid = threadIdx.x, b = blockIdx.x;
  const int w = tid >> 6, lane = tid & 63;
  const int q = lane >> 4, l15 = lane & 15;

  const int* order = (const int*)(ws + O_ORDER);
  const int* slen  = (const int*)(ws + O_SLEN);
  const signed char* wpk = (const signed char*)(ws + O_WPK);
  const float* upt = (const float*)(ws + O_USTP);
  const float* bsg = (const float*)(ws + O_BIAS);
  const unsigned short* wlin = (const unsigned short*)(ws + O_WLIN);

  // ---- prologue: chartab -> LDS, W kb0-6 -> VGPR, W kb7-9 -> LDS ----
  {
    long* d = (long*)&CT[0][0];
    const long* s = (const long*)(ws + O_CHT);
    #pragma unroll
    for (int ii = 0; ii < 4; ++ii) d[tid + 512 * ii] = s[tid + 512 * ii];
  }
  long wreg[7][8];
  #pragma unroll
  for (int kb = 0; kb < 7; ++kb)
    #pragma unroll
    for (int nt = 0; nt < 8; ++nt)
      wreg[kb][nt] = *(const long*)(wpk + (((w * 10 + kb) * 8 + nt) * 64 + lane) * 8);
  #pragma unroll
  for (int c = 0; c < 24; ++c) {
    int kb = c >> 3, nt = c & 7;
    *(long*)&WL[kb][w][nt][lane][0] =
        *(const long*)(wpk + (((w * 10 + 7 + kb) * 8 + nt) * 64 + lane) * 8);
  }
  float uq[8], bq[8];
  #pragma unroll
  for (int nt = 0; nt < 8; ++nt) {
    int n = (nt >> 1) * 256 + w * 32 + (nt & 1) * 16 + l15;
    uq[nt] = upt[n]; bq[nt] = bsg[n];
  }
  const int mh = w >> 2, nw = w & 3;
  float blv[4];
  #pragma unroll
  for (int nt = 0; nt < 4; ++nt) blv[nt] = blin[nw * 64 + nt * 16 + l15];

  // ---- two balanced slices: {b, 511-b} ----
  for (int sl = 0; sl < 2; ++sl) {
    const int s = sl ? (511 - b) : b;
    const int base = 64 * s;
    __syncthreads();                    // prologue / previous epilogue done

    { // zero Xb h-region (kb 2..9): 2048 longs
      long* p = (long*)&Xb[0][0][0][0];
      #pragma unroll
      for (int ii = 0; ii < 4; ++ii) {
        int idx = tid + 512 * ii;
        int mt = idx >> 9, rem = idx & 511;
        p[mt * 640 + 128 + rem] = 0L;
      }
    }
    if (tid < 256) {                    // load this slice's char indices
      int m = tid >> 2, part = tid & 3;
      int wid = order[base + m];
      *(i32x4*)&CW[m][part * 4] = *(const i32x4*)(cidx + wid * 16 + part * 4);
    }
    unsigned lenpk[4];
    #pragma unroll
    for (int mt = 0; mt < 4; ++mt) {
      int pbm = base + 16 * mt;
      unsigned l0 = (unsigned)slen[pbm + q * 4 + 0];
      unsigned l1 = (unsigned)slen[pbm + q * 4 + 1];
      unsigned l2 = (unsigned)slen[pbm + q * 4 + 2];
      unsigned l3 = (unsigned)slen[pbm + q * 4 + 3];
      lenpk[mt] = l0 | (l1 << 8) | (l2 << 16) | (l3 << 24);
    }
    const int Tm = slen[base + 63];
    __syncthreads();                    // CW + zeroing visible
    {                                   // stage x' for t=0
      int m = tid >> 3, c = tid & 7, kb = c >> 2, kq = c & 3;
      int ch = CW[m][0] & 255;
      *(long*)&Xb[m >> 4][kb][(m & 15) + 16 * kq][0] = *(const long*)&CT[ch][kb * 32 + kq * 8];
    }
    __syncthreads();

    float creg[4][2][4];
    #pragma unroll
    for (int mt = 0; mt < 4; ++mt)
      #pragma unroll
      for (int hs = 0; hs < 2; ++hs)
        #pragma unroll
        for (int r = 0; r < 4; ++r) creg[mt][hs][r] = 0.f;
    unsigned hpack[4][2];

    for (int t = 0; t < Tm; ++t) {
      // one straight-line body: 4 independent tile chains, no uniform branches
      #pragma unroll
      for (int mt = 0; mt < 4; ++mt) {
        i32x4 acc[8];
        #pragma unroll
        for (int nt = 0; nt < 8; ++nt) acc[nt] = (i32x4)0;
        #pragma unroll
        for (int kb = 0; kb < 7; ++kb) {
          long A = *(const long*)&Xb[mt][kb][lane][0];
          #pragma unroll
          for (int nt = 0; nt < 8; ++nt) acc[nt] = MFMAI8(A, wreg[kb][nt], acc[nt]);
        }
        #pragma unroll
        for (int kb = 7; kb < 10; ++kb) {
          long A = *(const long*)&Xb[mt][kb][lane][0];
          #pragma unroll
          for (int nt = 0; nt < 8; ++nt) {
            long Bv = *(const long*)&WL[kb - 7][w][nt][lane][0];
            acc[nt] = MFMAI8(A, Bv, acc[nt]);
          }
        }
        // gates (8 trans/unit, R7-validated algebra); C-layout row q*4+r, col l15
        #pragma unroll
        for (int hs = 0; hs < 2; ++hs) {
          unsigned hp = 0;
          #pragma unroll
          for (int r = 0; r < 4; ++r) {
            float gi = (float)acc[0 + hs][r] * uq[0 + hs] + bq[0 + hs];
            float gf = (float)acc[2 + hs][r] * uq[2 + hs] + bq[2 + hs];
            float gg = (float)acc[4 + hs][r] * uq[4 + hs] + bq[4 + hs];
            float go = (float)acc[6 + hs][r] * uq[6 + hs] + bq[6 + hs];
            gi = fminf(30.f, fmaxf(-30.f, gi));
            gf = fminf(30.f, fmaxf(-30.f, gf));
            gg = fminf(30.f, fmaxf(-30.f, gg));
            go = fminf(30.f, fmaxf(-30.f, go));
            float ei  = __builtin_amdgcn_exp2f(-1.44269504f * gi);
            float ef  = __builtin_amdgcn_exp2f(-1.44269504f * gf);
            float eg2 = __builtin_amdgcn_exp2f( 2.88539008f * gg);
            float eo  = __builtin_amdgcn_exp2f(-1.44269504f * go);
            float cold = creg[mt][hs][r];
            float cn = cold * __builtin_amdgcn_rcpf(1.f + ef) +
                       (eg2 - 1.f) * __builtin_amdgcn_rcpf((1.f + ei) * (1.f + eg2));
            float ec = __builtin_amdgcn_exp2f(2.88539008f * cn);
            float hn = (ec - 1.f) * __builtin_amdgcn_rcpf((1.f + eo) * (ec + 1.f));
            int lene = (int)((lenpk[mt] >> (8 * r)) & 255u);
            bool act = t < lene;                   // freeze past word length
            creg[mt][hs][r] = act ? cn : cold;
            int hq = (int)__builtin_rintf(127.f * hn);
            hq = hq < -127 ? -127 : (hq > 127 ? 127 : hq);
            hp |= ((unsigned)hq & 255u) << (8 * r);
          }
          hpack[mt][hs] = hp;
        }
      } // mt
      __syncthreads();                  // all Xb reads of step t done

      // h write-back (per-element predication keeps frozen words' final h)
      #pragma unroll
      for (int mt = 0; mt < 4; ++mt) {
        #pragma unroll
        for (int hs = 0; hs < 2; ++hs) {
          int kqp = hs * 2 + (l15 >> 3);
          #pragma unroll
          for (int r = 0; r < 4; ++r) {
            int lene = (int)((lenpk[mt] >> (8 * r)) & 255u);
            if (t < lene)
              Xb[mt][2 + w][(q * 4 + r) + 16 * kqp][l15 & 7] =
                  (signed char)((hpack[mt][hs] >> (8 * r)) & 255u);
          }
        }
      }
      if (t + 1 < Tm) {                 // stage x' for t+1
        int m = tid >> 3, c = tid & 7, kb = c >> 2, kq = c & 3;
        int ch = CW[m][t + 1] & 255;
        *(long*)&Xb[m >> 4][kb][(m & 15) + 16 * kq][0] = *(const long*)&CT[ch][kb * 32 + kq * 8];
      }
      __syncthreads();
    } // t

    // ---- fused final linear for this slice (bf16 MFMA) ----
    int widA[2];
    #pragma unroll
    for (int mi = 0; mi < 2; ++mi) widA[mi] = order[base + (2 * mh + mi) * 16 + l15];
    f32x4 fac[2][4];
    #pragma unroll
    for (int mi = 0; mi < 2; ++mi)
      #pragma unroll
      for (int nt = 0; nt < 4; ++nt) fac[mi][nt] = 0.0f;

    #pragma unroll
    for (int kf = 0; kf < 16; ++kf) {
      short8 Bn[4];
      #pragma unroll
      for (int nt = 0; nt < 4; ++nt)
        Bn[nt] = ((const short8*)wlin)[((nw * 4 + nt) * 16 + kf) * 64 + lane];
      short8 Am[2];
      #pragma unroll
      for (int mi = 0; mi < 2; ++mi) {
        if (kf < 8) {                   // word_emb fp32 -> bf16
          const f32x4* pa = (const f32x4*)(wemb + widA[mi] * 256 + kf * 32 + q * 8);
          f32x4 f0 = pa[0], f1 = pa[1];
          short8 A;
          A[0] = (short)f2b(f0[0]); A[1] = (short)f2b(f0[1]);
          A[2] = (short)f2b(f0[2]); A[3] = (short)f2b(f0[3]);
          A[4] = (short)f2b(f1[0]); A[5] = (short)f2b(f1[1]);
          A[6] = (short)f2b(f1[2]); A[7] = (short)f2b(f1[3]);
          Am[mi] = A;
        } else {                        // final h from Xb i8 -> bf16
          long ch = *(const long*)&Xb[2 * mh + mi][kf - 6][lane][0];
          short8 A;
          #pragma unroll
          for (int j = 0; j < 8; ++j) {
            int v = (int)(signed char)((ch >> (8 * j)) & 255);
            A[j] = (short)f2b((float)v * (1.f / 127.f));
          }
          Am[mi] = A;
        }
      }
      #pragma unroll
      for (int mi = 0; mi < 2; ++mi)
        #pragma unroll
        for (int nt = 0; nt < 4; ++nt)
          fac[mi][nt] = MFMA16(Am[mi], Bn[nt], fac[mi][nt]);
    }
    #pragma unroll
    for (int mi = 0; mi < 2; ++mi) {
      #pragma unroll
      for (int r = 0; r < 4; ++r) {
        int wid = order[base + (2 * mh + mi) * 16 + q * 4 + r];
        float* po = outp + wid * 256 + nw * 64 + l15;
        #pragma unroll
        for (int nt = 0; nt < 4; ++nt) {
          float v = fac[mi][nt][r] + blv[nt];
          po[nt * 16] = v > 0.f ? v : 0.f;
        }
      }
    }
  } // slice
}

extern "C" void kernel_launch(void* const* d_in, const int* in_sizes, int n_in,
                              void* d_out, int out_size, void* d_ws, size_t ws_size,
                              hipStream_t stream) {
  const int*   cidx = (const int*)d_in[0];
  const int*   clen = (const int*)d_in[1];
  const float* wemb = (const float*)d_in[2];
  const float* ech  = (const float*)d_in[3];
  const float* wih  = (const float*)d_in[4];
  const float* whh  = (const float*)d_in[5];
  const float* bih  = (const float*)d_in[6];
  const float* bhh  = (const float*)d_in[7];
  const float* wlin = (const float*)d_in[8];
  const float* blin = (const float*)d_in[9];
  float* outp = (float*)d_out;
  unsigned char* ws = (unsigned char*)d_ws;

  k_prepA<<<320, 256, 0, stream>>>(wih, whh, bih, bhh, ech, ws);
  k_prep1<<<1792, 256, 0, stream>>>(wih, whh, wlin, ws);
  k_sort<<<1, 1024, 0, stream>>>(clen, ws);
  k_main<<<256, 512, 139264, stream>>>(cidx, wemb, blin, outp, ws);
}